// Round 4
// baseline (50.271 us; speedup 1.0000x reference)
//
#include <hip/hip_runtime.h>

#define NCELLS (16384 * 7 * 7)   // 802816
#define CPB 256                  // cells per block
#define NBLOCKS (NCELLS / CPB)   // 3136, exact
#define CHUNK4 (CPB * 30 / 4)    // 1920 float4 per block
#define INV_BATCH (1.0f / 16384.0f)
#define EPS 1e-12f
#define IMG 448.0f
#define CELL (448.0f / 7.0f)     // 64
#define L_COORD 5.0f
#define L_NOOBJ 0.5f

__device__ __forceinline__ float iou_f(const float* bp, const float* bt) {
    float cxp = bp[0] * CELL, cyp = bp[1] * CELL;
    float wp  = bp[2] * IMG,  hp  = bp[3] * IMG;
    float cxt = bt[0] * CELL, cyt = bt[1] * CELL;
    float wt  = bt[2] * IMG,  ht  = bt[3] * IMG;
    float iw = fmaxf(fminf(cxp + wp * 0.5f, cxt + wt * 0.5f) -
                     fmaxf(cxp - wp * 0.5f, cxt - wt * 0.5f), 0.0f);
    float ih = fmaxf(fminf(cyp + hp * 0.5f, cyt + ht * 0.5f) -
                     fmaxf(cyp - hp * 0.5f, cyt - ht * 0.5f), 0.0f);
    float inter = iw * ih;
    float uni = wp * hp + wt * ht - inter;
    return inter / (uni + EPS);
}

__device__ __forceinline__ float coord_loss(const float* bp, const float* tb) {
    float xy = (bp[0] - tb[0]) * (bp[0] - tb[0]) + (bp[1] - tb[1]) * (bp[1] - tb[1]);
    float s2 = sqrtf(bp[2] + EPS) - sqrtf(tb[2] + EPS);
    float s3 = sqrtf(bp[3] + EPS) - sqrtf(tb[3] + EPS);
    return xy + s2 * s2 + s3 * s3;
}

// Kernel 1: stage y_pre through LDS with fully-coalesced float4 loads
// (T14 split: global->regs issued first, ds_write after), one cell/thread,
// one plain-store partial per block.
__global__ void __launch_bounds__(256) yolo_partial_kernel(
        const float* __restrict__ y_pre,
        const float* __restrict__ y_true,
        float* __restrict__ partial) {
    __shared__ float4 sp4[CHUNK4];                   // 30720 B
    float* sp = reinterpret_cast<float*>(sp4);

    const int tid = threadIdx.x;
    const int cell = blockIdx.x * CPB + tid;

    // ---- issue coalesced global loads into registers (dense lines) ----
    const float4* g4 = reinterpret_cast<const float4*>(y_pre)
                     + (size_t)blockIdx.x * CHUNK4;
    float4 st[8];
    #pragma unroll
    for (int i = 0; i < 7; ++i) st[i] = g4[tid + i * 256];
    if (tid < CHUNK4 - 7 * 256) st[7] = g4[tid + 7 * 256];   // 1920-1792=128

    // y_true: 8 floats, 32B-aligned, line-dense direct
    float tv[8];
    {
        const float4* t4 = reinterpret_cast<const float4*>(y_true) + (size_t)cell * 2;
        float4 ta = t4[0], tb4 = t4[1];
        tv[0] = ta.x; tv[1] = ta.y; tv[2] = ta.z; tv[3] = ta.w;
        tv[4] = tb4.x; tv[5] = tb4.y; tv[6] = tb4.z; tv[7] = tb4.w;
    }

    // ---- write staged data to LDS, one barrier ----
    #pragma unroll
    for (int i = 0; i < 7; ++i) sp4[tid + i * 256] = st[i];
    if (tid < CHUNK4 - 7 * 256) sp4[tid + 7 * 256] = st[7];
    __syncthreads();

    // ---- read own 30 floats from LDS ----
    float pv[30];
    {
        const float2* l2 = reinterpret_cast<const float2*>(sp + tid * 30);
        #pragma unroll
        for (int i = 0; i < 15; ++i) {
            float2 v = l2[i];
            pv[2 * i]     = v.x;
            pv[2 * i + 1] = v.y;
        }
    }

    float c1 = pv[4], c2 = pv[9];
    bool obj = (tv[0] != 0.0f);
    float loss;
    if (obj) {
        const float* tbx = tv + 1;
        float iou1 = iou_f(pv + 0, tbx);
        float iou2 = iou_f(pv + 5, tbx);
        float cl1 = coord_loss(pv + 0, tbx);
        float cl2 = coord_loss(pv + 5, tbx);
        int c = (int)tv[0] - 1;
        float cls = 0.0f;
        #pragma unroll
        for (int k = 0; k < 20; ++k) {
            float d = pv[10 + k] - (k == c ? 1.0f : 0.0f);
            cls += d * d;
        }
        float d1 = c1 - iou1, d2 = c2 - iou2;
        loss = d1 * d1 + d2 * d2 + L_COORD * (cl1 + cl2) + cls;
    } else {
        loss = L_NOOBJ * (c1 * c1 + c2 * c2);
    }
    float local = loss * INV_BATCH;

    // ---- wave-64 reduce ----
    #pragma unroll
    for (int off = 32; off > 0; off >>= 1)
        local += __shfl_down(local, off);

    // ---- block reduce -> one plain store ----
    __shared__ float wsum[4];
    int lane = tid & 63;
    int wid = tid >> 6;
    if (lane == 0) wsum[wid] = local;
    __syncthreads();
    if (tid == 0)
        partial[blockIdx.x] = wsum[0] + wsum[1] + wsum[2] + wsum[3];
}

// Kernel 2: single block sums the 3136 partials -> out[0]
__global__ void __launch_bounds__(256) yolo_final_kernel(
        const float* __restrict__ partial,
        float* __restrict__ out) {
    float local = 0.0f;
    for (int i = threadIdx.x; i < NBLOCKS; i += 256)
        local += partial[i];

    #pragma unroll
    for (int off = 32; off > 0; off >>= 1)
        local += __shfl_down(local, off);

    __shared__ float wsum[4];
    int lane = threadIdx.x & 63;
    int wid = threadIdx.x >> 6;
    if (lane == 0) wsum[wid] = local;
    __syncthreads();
    if (threadIdx.x == 0)
        out[0] = wsum[0] + wsum[1] + wsum[2] + wsum[3];
}

extern "C" void kernel_launch(void* const* d_in, const int* in_sizes, int n_in,
                              void* d_out, int out_size, void* d_ws, size_t ws_size,
                              hipStream_t stream) {
    const float* y_pre  = (const float*)d_in[0];
    const float* y_true = (const float*)d_in[1];
    float* out = (float*)d_out;
    float* partial = (float*)d_ws;   // 3136 * 4 B

    yolo_partial_kernel<<<NBLOCKS, 256, 0, stream>>>(y_pre, y_true, partial);
    yolo_final_kernel<<<1, 256, 0, stream>>>(partial, out);
}

// Round 5
// 29.486 us; speedup vs baseline: 1.7049x; 1.7049x over previous
//
#include <hip/hip_runtime.h>

#define NCELLS (16384 * 7 * 7)   // 802816
#define CPB 256                  // cells per block
#define NBLOCKS (NCELLS / CPB)   // 3136, exact
#define CHUNK4 (CPB * 30 / 4)    // 1920 float4 per block
#define INV_BATCH (1.0f / 16384.0f)
#define EPS 1e-12f
#define IMG 448.0f
#define CELL (448.0f / 7.0f)     // 64
#define L_COORD 5.0f
#define L_NOOBJ 0.5f

__device__ __forceinline__ float iou_f(const float* bp, const float* bt) {
    float cxp = bp[0] * CELL, cyp = bp[1] * CELL;
    float wp  = bp[2] * IMG,  hp  = bp[3] * IMG;
    float cxt = bt[0] * CELL, cyt = bt[1] * CELL;
    float wt  = bt[2] * IMG,  ht  = bt[3] * IMG;
    float iw = fmaxf(fminf(cxp + wp * 0.5f, cxt + wt * 0.5f) -
                     fmaxf(cxp - wp * 0.5f, cxt - wt * 0.5f), 0.0f);
    float ih = fmaxf(fminf(cyp + hp * 0.5f, cyt + ht * 0.5f) -
                     fmaxf(cyp - hp * 0.5f, cyt - ht * 0.5f), 0.0f);
    float inter = iw * ih;
    float uni = wp * hp + wt * ht - inter;
    return inter / (uni + EPS);
}

__device__ __forceinline__ float coord_loss(const float* bp, const float* tb) {
    float xy = (bp[0] - tb[0]) * (bp[0] - tb[0]) + (bp[1] - tb[1]) * (bp[1] - tb[1]);
    float s2 = sqrtf(bp[2] + EPS) - sqrtf(tb[2] + EPS);
    float s3 = sqrtf(bp[3] + EPS) - sqrtf(tb[3] + EPS);
    return xy + s2 * s2 + s3 * s3;
}

// Kernel 1: R2's proven spill-free LDS staging (direct global->LDS assignment,
// coalesced float4 lines), one cell/thread, plain-store partial per block.
__global__ void __launch_bounds__(256) yolo_partial_kernel(
        const float* __restrict__ y_pre,
        const float* __restrict__ y_true,
        float* __restrict__ partial) {
    __shared__ float4 sp4[CHUNK4];                   // 30720 B
    float* sp = reinterpret_cast<float*>(sp4);

    const int tid = threadIdx.x;
    const int cell = blockIdx.x * CPB + tid;

    const float4* g4 = reinterpret_cast<const float4*>(y_pre)
                     + (size_t)blockIdx.x * CHUNK4;
    #pragma unroll
    for (int i = 0; i < 8; ++i) {
        int idx = tid + i * 256;
        if (idx < CHUNK4) sp4[idx] = g4[idx];        // short live range, no spill (R2)
    }
    __syncthreads();

    // y_true: 8 floats, 32B-aligned, line-dense direct
    float tv[8];
    {
        const float4* t4 = reinterpret_cast<const float4*>(y_true) + (size_t)cell * 2;
        float4 ta = t4[0], tb4 = t4[1];
        tv[0] = ta.x; tv[1] = ta.y; tv[2] = ta.z; tv[3] = ta.w;
        tv[4] = tb4.x; tv[5] = tb4.y; tv[6] = tb4.z; tv[7] = tb4.w;
    }

    // own 30 floats from LDS (float2 reads, ~4-way conflict = negligible)
    float pv[30];
    {
        const float2* l2 = reinterpret_cast<const float2*>(sp + tid * 30);
        #pragma unroll
        for (int i = 0; i < 15; ++i) {
            float2 v = l2[i];
            pv[2 * i]     = v.x;
            pv[2 * i + 1] = v.y;
        }
    }

    float c1 = pv[4], c2 = pv[9];
    bool obj = (tv[0] != 0.0f);
    float loss;
    if (obj) {
        const float* tbx = tv + 1;
        float iou1 = iou_f(pv + 0, tbx);
        float iou2 = iou_f(pv + 5, tbx);
        float cl1 = coord_loss(pv + 0, tbx);
        float cl2 = coord_loss(pv + 5, tbx);
        int c = (int)tv[0] - 1;
        float cls = 0.0f;
        #pragma unroll
        for (int k = 0; k < 20; ++k) {
            float d = pv[10 + k] - (k == c ? 1.0f : 0.0f);
            cls += d * d;
        }
        float d1 = c1 - iou1, d2 = c2 - iou2;
        loss = d1 * d1 + d2 * d2 + L_COORD * (cl1 + cl2) + cls;
    } else {
        loss = L_NOOBJ * (c1 * c1 + c2 * c2);
    }
    float local = loss * INV_BATCH;

    // wave-64 reduce
    #pragma unroll
    for (int off = 32; off > 0; off >>= 1)
        local += __shfl_down(local, off);

    // block reduce -> one plain store
    __shared__ float wsum[4];
    int lane = tid & 63;
    int wid = tid >> 6;
    if (lane == 0) wsum[wid] = local;
    __syncthreads();
    if (tid == 0)
        partial[blockIdx.x] = wsum[0] + wsum[1] + wsum[2] + wsum[3];
}

// Kernel 2: single block sums the 3136 partials -> out[0]
__global__ void __launch_bounds__(256) yolo_final_kernel(
        const float* __restrict__ partial,
        float* __restrict__ out) {
    float local = 0.0f;
    for (int i = threadIdx.x; i < NBLOCKS; i += 256)
        local += partial[i];

    #pragma unroll
    for (int off = 32; off > 0; off >>= 1)
        local += __shfl_down(local, off);

    __shared__ float wsum[4];
    int lane = threadIdx.x & 63;
    int wid = threadIdx.x >> 6;
    if (lane == 0) wsum[wid] = local;
    __syncthreads();
    if (threadIdx.x == 0)
        out[0] = wsum[0] + wsum[1] + wsum[2] + wsum[3];
}

extern "C" void kernel_launch(void* const* d_in, const int* in_sizes, int n_in,
                              void* d_out, int out_size, void* d_ws, size_t ws_size,
                              hipStream_t stream) {
    const float* y_pre  = (const float*)d_in[0];
    const float* y_true = (const float*)d_in[1];
    float* out = (float*)d_out;
    float* partial = (float*)d_ws;   // 3136 * 4 B

    yolo_partial_kernel<<<NBLOCKS, 256, 0, stream>>>(y_pre, y_true, partial);
    yolo_final_kernel<<<1, 256, 0, stream>>>(partial, out);
}